// Round 5
// baseline (175.527 us; speedup 1.0000x reference)
//
#include <hip/hip_runtime.h>
#include <stdint.h>

// InformPooling, two-pass chunk-sum scheme. Pass 1 now uses global_load_lds DMA.
//   value0 [8,16384,128] r=1.0 ; value1 [8,8192,128] r=0.5 ; value2 [8,4096,256] r=0.25
//   start/duration [8,512]; out [8,512,512] f32 (channels concat 128|128|256).
//
// R1-R3 evidence: every VGPR-return load structure for pass 1 plateaus at ~3 TB/s
// (short waves, float4, manual prefetch all equal; R3's prefetch was deleted by the
// register allocator - VGPR_Count 36). R0's long-stream kernel hit 5.9 TB/s from
// LLC-warm inputs; m97 GEMM staging via global_load_lds hit ~26 TB/s aggregate.
// -> Pass 1 = LDS-DMA staging: 1024 resident blocks x 4 tiles; per tile stage 32 KB
//    contiguous (8 fire-and-forget 16B-DMA issues/thread), barrier, sum kC=8-row
//    chunks from LDS (ds_read_b128, conflict-free), store S. No dispatch churn,
//    no VGPR pressure, deep load queue.
// Pass 2 (gather, unchanged): per (b,n,pool) wave; interior from S, <=7 edge rows
// direct; ~VMEM ceiling already.

constexpr int   kB   = 8;
constexpr int   kN   = 512;
constexpr float kEps = 1e-3f;
constexpr int   kC   = 8;  // chunk rows

// float offsets into ws: S0 flat [16384][128], S1 [8192][128], S2 [4096][256]
constexpr size_t S0_OFF = 0;
constexpr size_t S1_OFF = (size_t)16384 * 128;
constexpr size_t S2_OFF = S1_OFF + (size_t)8192 * 128;

typedef __attribute__((address_space(3))) uint32_t as3_u32;
typedef __attribute__((address_space(1))) uint32_t as1_u32;

static __device__ __forceinline__ void ld16(void* lds, const void* g) {
    // dst LDS address is wave-uniform base; HW scatters to base + lane*16.
    __builtin_amdgcn_global_load_lds((const as1_u32*)g, (as3_u32*)lds, 16, 0, 0);
}

static __device__ __forceinline__ float4 f4add(float4 a, float4 b) {
    a.x += b.x; a.y += b.y; a.z += b.z; a.w += b.w; return a;
}

__global__ __launch_bounds__(256) void chunk_sum_kernel(
    const float* __restrict__ v0, const float* __restrict__ v1,
    const float* __restrict__ v2, float* __restrict__ ws)
{
    __shared__ float tile[8192];          // 32 KB: 64x512B rows (pool0/1) or 32x1KB (pool2)
    const int blk  = blockIdx.x;          // [0,1024)
    const int wv   = threadIdx.x >> 6;    // wave in block [0,4)
    const int lane = threadIdx.x & 63;

    const float* v; float* S; int pool; int t0;
    if (blk < 512)      { v = v0; S = ws + S0_OFF; pool = 0; t0 = blk * 4; }          // 2048 tiles
    else if (blk < 768) { v = v1; S = ws + S1_OFF; pool = 1; t0 = (blk - 512) * 4; }  // 1024 tiles
    else                { v = v2; S = ws + S2_OFF; pool = 2; t0 = (blk - 768) * 4; }  // 1024 tiles

    // Every tile is 32768 bytes of the flat [rows][ch] array, regardless of pool.
    const char* gb = (const char*)v + (size_t)t0 * 32768 + wv * 8192 + lane * 16;
    char*       lb = (char*)tile + wv * 8192;   // wave-uniform LDS base
    const float4* T4 = (const float4*)tile;
    const int h = lane >> 5, q = lane & 31;

    for (int it = 0; it < 4; it++) {
        const int t = t0 + it;
        // ---- stage 32 KB tile: 8 fire-and-forget 1KB-per-wave DMA issues ----
#pragma unroll
        for (int j = 0; j < 8; j++)
            ld16(lb + j * 1024, gb + j * 1024);
        __syncthreads();                  // drains vmcnt; tile complete

        // ---- sum kC=8-row chunks from LDS, store to S ----
        if (pool < 2) {
            // tile = 8 chunks of 8 rows x 32 float4. wave wv does chunks wv, wv+4.
#pragma unroll
            for (int kk = 0; kk < 2; kk++) {
                const int k = wv + kk * 4;
                float4 a = make_float4(0, 0, 0, 0);
#pragma unroll
                for (int rr = 0; rr < 4; rr++) {
                    const int row = k * 8 + h + rr * 2;   // halves split rows by parity
                    a = f4add(a, T4[row * 32 + q]);
                }
                a.x += __shfl_xor(a.x, 32);
                a.y += __shfl_xor(a.y, 32);
                a.z += __shfl_xor(a.z, 32);
                a.w += __shfl_xor(a.w, 32);
                if (lane < 32)
                    ((float4*)(S + (size_t)(t * 8 + k) * 128))[q] = a;
            }
        } else {
            // tile = 4 chunks of 8 rows x 64 float4. wave wv does chunk wv.
            float4 a = make_float4(0, 0, 0, 0);
#pragma unroll
            for (int r = 0; r < 8; r++)
                a = f4add(a, T4[(wv * 8 + r) * 64 + lane]);
            ((float4*)(S + (size_t)(t * 4 + wv) * 256))[lane] = a;
        }
        __syncthreads();                  // LDS reads done before next stage
        gb += 32768;
    }
}

__global__ __launch_bounds__(256) void gather_kernel(
    const float* __restrict__ v0, const float* __restrict__ v1,
    const float* __restrict__ v2, const float* __restrict__ start,
    const float* __restrict__ dur, const float* __restrict__ ws,
    float* __restrict__ out)
{
    const int wave = threadIdx.x >> 6;
    const int lane = threadIdx.x & 63;
    const int half = lane >> 5;
    const int q    = lane & 31;
    const int bn   = blockIdx.x * 4 + wave;   // [0, 4096)
    const int b    = bn >> 9;
    const int pool = blockIdx.y;

    const float st = start[bn];
    const float du = dur[bn];
    float* outbase = out + (size_t)bn * 512;

    if (pool < 2) {
        const float* v  = (pool == 0) ? v0 : v1;
        const float* S  = ws + ((pool == 0) ? S0_OFF : S1_OFF);
        const int    T  = (pool == 0) ? 16384 : 8192;
        const int    NC = T / kC;
        const float  r  = (pool == 0) ? 1.0f : 0.5f;
        const int s = min((int)floorf(st * r), T - 1);
        const int e = min((int)ceilf((st + du + kEps) * r), T - 1);
        const int cnt = e - s;

        float4 a = make_float4(0, 0, 0, 0);
        if (cnt > 0) {
            const float4* vp = (const float4*)(v + (size_t)b * T * 128) + q;   // row t: vp[t*32]
            const int cs = (s + kC - 1) >> 3;
            const int ce = e >> 3;
            if (ce > cs) {
                const float4* Sp = (const float4*)(S + (size_t)b * NC * 128) + q; // chunk c: Sp[c*32]
                for (int c = cs + half; c < ce; c += 2)
                    a = f4add(a, Sp[(size_t)c * 32]);
                for (int t = s + half; t < cs * kC; t += 2)      // front edge (<=7 rows)
                    a = f4add(a, vp[(size_t)t * 32]);
                for (int t = ce * kC + half; t < e; t += 2)      // back edge (<=7 rows)
                    a = f4add(a, vp[(size_t)t * 32]);
            } else {
                for (int t = s + half; t < e; t += 2)            // short segment
                    a = f4add(a, vp[(size_t)t * 32]);
            }
        }
        a.x += __shfl_xor(a.x, 32);
        a.y += __shfl_xor(a.y, 32);
        a.z += __shfl_xor(a.z, 32);
        a.w += __shfl_xor(a.w, 32);
        float4 res = make_float4(0, 0, 0, 0);
        if (cnt > 0) {
            const float c = (float)cnt;
            res.x = a.x / c; res.y = a.y / c; res.z = a.z / c; res.w = a.w / c;
        }
        if (lane < 32)
            ((float4*)(outbase + (pool == 0 ? 0 : 128)))[q] = res;
    } else {
        const int   T  = 4096;
        const int   NC = T / kC;
        const float r  = 0.25f;
        const int s = min((int)floorf(st * r), T - 1);
        const int e = min((int)ceilf((st + du + kEps) * r), T - 1);
        const int cnt = e - s;

        float4 a0 = make_float4(0, 0, 0, 0), a1 = make_float4(0, 0, 0, 0);
        if (cnt > 0) {
            const float4* vp = (const float4*)(v2 + (size_t)b * T * 256) + lane;  // row t: vp[t*64]
            const int cs = (s + kC - 1) >> 3;
            const int ce = e >> 3;
            if (ce > cs) {
                const float4* Sp = (const float4*)(ws + S2_OFF + (size_t)b * NC * 256) + lane;
                int c = cs;
                for (; c + 2 <= ce; c += 2) {
                    a0 = f4add(a0, Sp[(size_t)c * 64]);
                    a1 = f4add(a1, Sp[(size_t)(c + 1) * 64]);
                }
                if (c < ce) a0 = f4add(a0, Sp[(size_t)c * 64]);
                for (int t = s; t < cs * kC; t++) a0 = f4add(a0, vp[(size_t)t * 64]);
                for (int t = ce * kC; t < e; t++) a1 = f4add(a1, vp[(size_t)t * 64]);
            } else {
                for (int t = s; t < e; t++) a0 = f4add(a0, vp[(size_t)t * 64]);
            }
        }
        float4 res = make_float4(0, 0, 0, 0);
        if (cnt > 0) {
            const float c = (float)cnt;
            res.x = (a0.x + a1.x) / c;
            res.y = (a0.y + a1.y) / c;
            res.z = (a0.z + a1.z) / c;
            res.w = (a0.w + a1.w) / c;
        }
        ((float4*)(outbase + 256))[lane] = res;
    }
}

extern "C" void kernel_launch(void* const* d_in, const int* in_sizes, int n_in,
                              void* d_out, int out_size, void* d_ws, size_t ws_size,
                              hipStream_t stream) {
    const float* v0    = (const float*)d_in[0];
    const float* v1    = (const float*)d_in[1];
    const float* v2    = (const float*)d_in[2];
    const float* start = (const float*)d_in[3];
    const float* dur   = (const float*)d_in[4];
    float*       out   = (float*)d_out;
    float*       ws    = (float*)d_ws;

    // Pass 1: 1024 resident blocks (512 pool0 + 256 pool1 + 256 pool2), 4 tiles each
    chunk_sum_kernel<<<dim3(1024), 256, 0, stream>>>(v0, v1, v2, ws);
    // Pass 2: one wave per (bn, pool)
    gather_kernel<<<dim3(kB * kN / 4, 3), 256, 0, stream>>>(v0, v1, v2, start, dur, ws, out);
}